// Round 6
// baseline (298.342 us; speedup 1.0000x reference)
//
#include <hip/hip_runtime.h>
#include <hip/hip_bf16.h>
#include <math.h>

#define N_TOK 16384
#define DIM   2048
#define NE    64
#define TOPK  9

#define DC       64            // k-elements per chunk
#define NCHUNK   (DIM / DC)    // 32
#define G_ROWS   16            // rows per GEMM block
#define R_ROWS   32            // rows per router block (4 waves x 8)

typedef short  short8  __attribute__((ext_vector_type(8)));
typedef float  float4_ __attribute__((ext_vector_type(4)));
typedef unsigned short ushort_t;

__device__ __forceinline__ unsigned pk2(float a, float b) {
    float2 f; f.x = a; f.y = b;
    __hip_bfloat162 h = __float22bfloat162_rn(f);   // low16 = bf16(a)
    unsigned u;
    __builtin_memcpy(&u, &h, 4);
    return u;
}

// 8 fp32 -> bf16 hi frag + bf16 lo frag (2-term split)
__device__ __forceinline__ void cvt8(const float4_ va, const float4_ vb,
                                     short8* h, short8* l) {
    union { short8 s; unsigned u[4]; } H, L;
    const float f[8] = {va[0], va[1], va[2], va[3], vb[0], vb[1], vb[2], vb[3]};
#pragma unroll
    for (int i = 0; i < 4; ++i) {
        const float a = f[2 * i], b = f[2 * i + 1];
        const unsigned p = pk2(a, b);
        H.u[i] = p;
        const float ha = __uint_as_float(p << 16);
        const float hb = __uint_as_float(p & 0xffff0000u);
        L.u[i] = pk2(a - ha, b - hb);
    }
    *h = H.s; *l = L.s;
}

__device__ __forceinline__ void wave_max64_2(float& a, float& b) {
#pragma unroll
    for (int off = 32; off > 0; off >>= 1) {
        const float ax = __shfl_xor(a, off, 64);
        const float bx = __shfl_xor(b, off, 64);
        a = fmaxf(a, ax);
        b = fmaxf(b, bx);
    }
}

__device__ __forceinline__ void wave_sum64_3(float& a, float& b, float& c) {
#pragma unroll
    for (int off = 32; off > 0; off >>= 1) {
        const float ax = __shfl_xor(a, off, 64);
        const float bx = __shfl_xor(b, off, 64);
        const float cx = __shfl_xor(c, off, 64);
        a += ax;
        b += bx;
        c += cx;
    }
}

// ---- prep: Wr|Wn (fp32, D x 64 each) -> B-fragment-ordered bf16 hi/lo ----
// slot s=(kcg*8+ct)*2+t holds 512 bf16: elem l*8+j = B[k=kcg*32+(l>>4)*8+j][n=ct*16+(l&15)]
__global__ __launch_bounds__(256)
void prep_w(const float* __restrict__ Wr, const float* __restrict__ Wn,
            ushort_t* __restrict__ wsW)
{
    const int gid = blockIdx.x * 256 + threadIdx.x;   // [0, 64*8*64)
    const int l   = gid & 63;
    const int ct  = (gid >> 6) & 7;
    const int kcg = gid >> 9;                         // 0..63
    const int n   = ct * 16 + (l & 15);
    const int k0  = kcg * 32 + (l >> 4) * 8;
    const float* src = (n < NE) ? (Wr + n) : (Wn + (n - NE));
    union { short8 s; ushort_t us[8]; } H, L;
#pragma unroll
    for (int j = 0; j < 8; ++j) {
        const float v = src[(size_t)(k0 + j) * NE];
        const unsigned uv = __float_as_uint(v);
        const unsigned hb = (uv + 0x7fffu + ((uv >> 16) & 1u)) & 0xffff0000u;
        const float lo = v - __uint_as_float(hb);
        const unsigned ul = __float_as_uint(lo);
        H.us[j] = (ushort_t)(hb >> 16);
        L.us[j] = (ushort_t)((ul + 0x7fffu + ((ul >> 16) & 1u)) >> 16);
    }
    const size_t s0 = (size_t)(kcg * 8 + ct) * 2;     // slot pair index
    *(short8*)(wsW + s0 * 512 + l * 8)         = H.s;
    *(short8*)(wsW + (s0 + 1) * 512 + l * 8)   = L.s;
}

// ---- register pipeline stages ----
struct AFrag { float4_ v[4]; };                 // [kc*2 + half]
struct BFrag { short8 h[2][2]; short8 l[2][2]; };

__device__ __forceinline__ void load_a(const float* __restrict__ p, AFrag& a) {
    a.v[0] = *(const float4_*)(p);
    a.v[1] = *(const float4_*)(p + 4);
    a.v[2] = *(const float4_*)(p + 32);
    a.v[3] = *(const float4_*)(p + 36);
}

__device__ __forceinline__ void load_b(const char* __restrict__ wsB,
                                       int ch, int w, int lane, BFrag& b) {
#pragma unroll
    for (int kc = 0; kc < 2; ++kc)
#pragma unroll
        for (int cc = 0; cc < 2; ++cc) {
            const size_t off = (size_t)(((ch * 2 + kc) * 8) + 2 * w + cc) * 2048
                             + (size_t)lane * 16;
            b.h[kc][cc] = *(const short8*)(wsB + off);
            b.l[kc][cc] = *(const short8*)(wsB + off + 1024);
        }
}

__device__ __forceinline__ void compute_chunk(const AFrag& a, const BFrag& b,
                                              float4_ (&acc)[2]) {
#pragma unroll
    for (int kc = 0; kc < 2; ++kc) {
        short8 ah, al;
        cvt8(a.v[kc * 2], a.v[kc * 2 + 1], &ah, &al);
#pragma unroll
        for (int cc = 0; cc < 2; ++cc) {
            acc[cc] = __builtin_amdgcn_mfma_f32_16x16x32_bf16(ah, b.h[kc][cc], acc[cc], 0, 0, 0);
            acc[cc] = __builtin_amdgcn_mfma_f32_16x16x32_bf16(al, b.h[kc][cc], acc[cc], 0, 0, 0);
            acc[cc] = __builtin_amdgcn_mfma_f32_16x16x32_bf16(ah, b.l[kc][cc], acc[cc], 0, 0, 0);
        }
    }
}

// ---- GEMM: x[16384x2048] @ [Wr|Wn] -> logits[16384x128] (raw|noise) ----
// Pure-register dataflow: no LDS, no barriers. Loop-carried 2-stage pipeline:
// loads for chunk i+2 issue right after chunk i's compute; use is across the
// back-edge, so the scheduler cannot sink them into their consumers.
__global__ __launch_bounds__(256, 3)
void gemm_logits(const float* __restrict__ x,
                 const ushort_t* __restrict__ wsW,
                 float* __restrict__ logits)
{
    const int t    = threadIdx.x;
    const int lane = t & 63;
    const int w    = t >> 6;          // wave 0..3, owns col-tiles {2w, 2w+1}
    const int c4   = lane & 15;
    const int q    = lane >> 4;
    const int row0 = blockIdx.x * G_ROWS;

    // A fragment base: lane l covers A[m=c4][k = q*8 + j] of each 16x32 slab
    const float* pA = x + (size_t)(row0 + c4) * DIM + q * 8;
    const char*  wsB = (const char*)wsW;

    float4_ acc[2];
    acc[0] = (float4_)(0.f);
    acc[1] = (float4_)(0.f);

    AFrag aX, aY;
    BFrag bX, bY;
    load_a(pA + 0 * DC, aX);
    load_b(wsB, 0, w, lane, bX);
    load_a(pA + 1 * DC, aY);
    load_b(wsB, 1, w, lane, bY);

#pragma unroll 1
    for (int i = 0; i < NCHUNK - 2; i += 2) {
        compute_chunk(aX, bX, acc);
        load_a(pA + (i + 2) * DC, aX);
        load_b(wsB, i + 2, w, lane, bX);
        compute_chunk(aY, bY, acc);
        load_a(pA + (i + 3) * DC, aY);
        load_b(wsB, i + 3, w, lane, bY);
    }
    compute_chunk(aX, bX, acc);
    compute_chunk(aY, bY, acc);

    // store: C/D mapping col=lane&15, row=(lane>>4)*4+reg
#pragma unroll
    for (int cc = 0; cc < 2; ++cc) {
        const int colg = (2 * w + cc) * 16 + c4;   // 0..127 (raw|noise)
#pragma unroll
        for (int v = 0; v < 4; ++v) {
            const int row = q * 4 + v;
            logits[(size_t)(row0 + row) * 128 + colg] = acc[cc][v];
        }
    }
}

// ---- router: per-row top-k / softmaxes / load-balancing stats ----
__global__ __launch_bounds__(256)
void router(const float* __restrict__ logits,
            const float* __restrict__ br,
            const float* __restrict__ bn,
            const float* __restrict__ noise_eps,
            const float* __restrict__ gumbel,
            float* __restrict__ out)
{
    __shared__ float red[512];
    const int t    = threadIdx.x;
    const int lane = t & 63;
    const int w    = t >> 6;
    const int row0 = blockIdx.x * R_ROWS + w * 8;

    const float br_l = br[lane];
    const float bn_l = bn[lane];

    // prefetch all 8 rows x 4 streams (issues 32 independent loads)
    float rawv[8], nlv[8], epsv[8], gumv[8];
#pragma unroll
    for (int r = 0; r < 8; ++r) {
        const size_t row = (size_t)(row0 + r);
        rawv[r] = logits[row * 128 + lane];
        nlv[r]  = logits[row * 128 + 64 + lane];
        epsv[r] = noise_eps[row * NE + lane];
        gumv[r] = gumbel  [row * NE + lane];
    }

    float imp_acc = 0.f, load_acc = 0.f;
    float* out_em   = out;
    float* out_rp   = out + (size_t)N_TOK * NE;
    float* out_imp  = out + (size_t)2 * N_TOK * NE;
    float* out_load = out_imp + NE;

#pragma unroll 2
    for (int r = 0; r < 8; ++r) {
        const int row = row0 + r;
        const float raw = rawv[r] + br_l;
        const float nl  = nlv[r]  + bn_l;
        const float sd = fmaxf(nl, 0.f) + log1pf(expf(-fabsf(nl))) + 0.01f;
        const float noisy = fmaf(epsv[r], sd, raw);

        // ---- threshold = 9th largest via ballot binary search (bit-exact) ----
        const unsigned uk  = __float_as_uint(noisy);
        const unsigned key = uk ^ ((uk & 0x80000000u) ? 0xFFFFFFFFu : 0x80000000u);
        unsigned res = 0;
#pragma unroll
        for (int bit = 31; bit >= 0; --bit) {
            const unsigned cand = res | (1u << bit);
            const int cnt = __popcll(__ballot(key >= cand));
            if (cnt >= TOPK) res = cand;
        }
        const float thr  = __uint_as_float(res ^ ((res & 0x80000000u) ? 0x80000000u : 0xFFFFFFFFu));
        const float hard = (key >= res) ? 1.f : 0.f;

        // fused reductions: one dual-max chain, one triple-sum chain
        const float g = noisy + gumv[r];
        float mg = g, mr = raw;
        wave_max64_2(mg, mr);

        const float eg = expf(g - mg);
        const float en = expf(noisy - thr);   // softmax shift-invariant
        const float er = expf(raw - mr);
        float sg = eg, sn = en, sr = er;
        wave_sum64_3(sg, sn, sr);

        const float ms = eg / sg;
        const float em = (hard - ms) + ms;
        const float rp = en / sn;
        imp_acc += er / sr;

        const float z = (thr - raw) / sd;
        load_acc += 0.5f * erfcf(z * 45.254833995939045f);

        out_em[(size_t)row * NE + lane] = em;
        out_rp[(size_t)row * NE + lane] = rp;
    }

    red[w * 64 + lane]       = imp_acc;
    red[256 + w * 64 + lane] = load_acc;
    __syncthreads();
    if (w == 0) {
        const float s1 = red[lane] + red[64 + lane] + red[128 + lane] + red[192 + lane];
        const float s2 = red[256 + lane] + red[320 + lane] + red[384 + lane] + red[448 + lane];
        atomicAdd(&out_imp[lane], s1);
        atomicAdd(&out_load[lane], s2);
    }
}

extern "C" void kernel_launch(void* const* d_in, const int* in_sizes, int n_in,
                              void* d_out, int out_size, void* d_ws, size_t ws_size,
                              hipStream_t stream)
{
    const float* x         = (const float*)d_in[0];
    const float* Wr        = (const float*)d_in[1];
    const float* br        = (const float*)d_in[2];
    const float* Wn        = (const float*)d_in[3];
    const float* bn        = (const float*)d_in[4];
    const float* noise_eps = (const float*)d_in[5];
    const float* gumbel    = (const float*)d_in[6];
    float* out = (float*)d_out;

    ushort_t* wsW = (ushort_t*)d_ws;                       // 1 MB B-fragments
    float* logits = (float*)((char*)d_ws + (1 << 20));     // 8 MB raw|noise

    (void)hipMemsetAsync((char*)d_out + (size_t)2 * N_TOK * NE * sizeof(float), 0,
                         2 * NE * sizeof(float), stream);
    prep_w<<<128, 256, 0, stream>>>(Wr, Wn, wsW);
    gemm_logits<<<N_TOK / G_ROWS, 256, 0, stream>>>(x, wsW, logits);
    router<<<N_TOK / R_ROWS, 256, 0, stream>>>(logits, br, bn, noise_eps, gumbel, out);
}